// Round 1
// baseline (1843.211 us; speedup 1.0000x reference)
//
#include <hip/hip_runtime.h>

#define RES 32
#define R3 (RES * RES * RES)

// ---------------------------------------------------------------------------
// Kernel 1: per-batch coordinate stats.
// One block per batch. Computes mean over N for each of 3 dims, then
// max ||c - mean|| over N. Writes mean[b*3+c] and maxn[b].
// ---------------------------------------------------------------------------
__global__ void stats_kernel(const float* __restrict__ coords,
                             float* __restrict__ mean_out,
                             float* __restrict__ maxn_out,
                             int N) {
    const int b = blockIdx.x;
    const float* cb = coords + (size_t)b * 3 * N;

    float s0 = 0.f, s1 = 0.f, s2 = 0.f;
    for (int n = threadIdx.x; n < N; n += blockDim.x) {
        s0 += cb[n];
        s1 += cb[N + n];
        s2 += cb[2 * N + n];
    }

    __shared__ float red0[16], red1[16], red2[16];
    __shared__ float mean_s[3];
    const int lane = threadIdx.x & 63;
    const int wave = threadIdx.x >> 6;
    const int nwaves = blockDim.x >> 6;

    for (int off = 32; off; off >>= 1) {
        s0 += __shfl_down(s0, off);
        s1 += __shfl_down(s1, off);
        s2 += __shfl_down(s2, off);
    }
    if (lane == 0) { red0[wave] = s0; red1[wave] = s1; red2[wave] = s2; }
    __syncthreads();
    if (threadIdx.x == 0) {
        float t0 = 0.f, t1 = 0.f, t2 = 0.f;
        for (int w = 0; w < nwaves; ++w) { t0 += red0[w]; t1 += red1[w]; t2 += red2[w]; }
        mean_s[0] = t0 / (float)N;
        mean_s[1] = t1 / (float)N;
        mean_s[2] = t2 / (float)N;
    }
    __syncthreads();
    const float m0 = mean_s[0], m1 = mean_s[1], m2 = mean_s[2];

    float mx = 0.f;
    for (int n = threadIdx.x; n < N; n += blockDim.x) {
        float a = cb[n] - m0;
        float c = cb[N + n] - m1;
        float d = cb[2 * N + n] - m2;
        float sq = a * a + c * c + d * d;
        mx = fmaxf(mx, sq);
    }
    for (int off = 32; off; off >>= 1) mx = fmaxf(mx, __shfl_down(mx, off));
    if (lane == 0) red0[wave] = mx;
    __syncthreads();
    if (threadIdx.x == 0) {
        float t = 0.f;
        for (int w = 0; w < nwaves; ++w) t = fmaxf(t, red0[w]);
        mean_out[b * 3 + 0] = mean_s[0];
        mean_out[b * 3 + 1] = mean_s[1];
        mean_out[b * 3 + 2] = mean_s[2];
        maxn_out[b] = sqrtf(t);
    }
}

// ---------------------------------------------------------------------------
// Kernel 2: normalize coords, write norm_coords output, scatter-add features
// and counts into the voxel grid (vox region of d_out, layout (B, D, R3)).
// One thread per point; inner loop over D with coalesced feature reads.
// ---------------------------------------------------------------------------
__global__ void scatter_kernel(const float* __restrict__ coords,
                               const float* __restrict__ feats,
                               const float* __restrict__ mean,
                               const float* __restrict__ maxn,
                               float* __restrict__ vox_out,   // (B, D, R3), pre-zeroed
                               float* __restrict__ nc_out,    // (B, 3, N)
                               float* __restrict__ cnt,       // (B, R3), pre-zeroed
                               int D, int N) {
    const int n = blockIdx.x * blockDim.x + threadIdx.x;
    const int b = blockIdx.y;
    if (n >= N) return;

    const float* cb = coords + (size_t)b * 3 * N;
    const float m0 = mean[b * 3 + 0];
    const float m1 = mean[b * 3 + 1];
    const float m2 = mean[b * 3 + 2];
    const float denom = 2.0f * maxn[b];

    float c0 = (cb[n] - m0) / denom + 0.5f;
    float c1 = (cb[N + n] - m1) / denom + 0.5f;
    float c2 = (cb[2 * N + n] - m2) / denom + 0.5f;

    float v0 = fminf(fmaxf(c0 * (float)RES, 0.f), (float)(RES - 1));
    float v1 = fminf(fmaxf(c1 * (float)RES, 0.f), (float)(RES - 1));
    float v2 = fminf(fmaxf(c2 * (float)RES, 0.f), (float)(RES - 1));

    float* ncb = nc_out + (size_t)b * 3 * N;
    ncb[n] = v0;
    ncb[N + n] = v1;
    ncb[2 * N + n] = v2;

    // round-half-to-even to match jnp.round
    const int i0 = (int)rintf(v0);
    const int i1 = (int)rintf(v1);
    const int i2 = (int)rintf(v2);
    const int idx = i0 * RES * RES + i1 * RES + i2;

    atomicAdd(&cnt[(size_t)b * R3 + idx], 1.0f);

    const float* fb = feats + (size_t)b * D * N + n;
    float* ob = vox_out + (size_t)b * D * R3 + idx;
    for (int d = 0; d < D; ++d) {
        atomicAdd(&ob[(size_t)d * R3], fb[(size_t)d * N]);
    }
}

// ---------------------------------------------------------------------------
// Kernel 3: divide voxel sums by max(count, 1), in place.
// Thread per voxel, loop over D; consecutive threads -> consecutive v
// -> coalesced access for every d.
// ---------------------------------------------------------------------------
__global__ void finalize_kernel(float* __restrict__ vox,
                                const float* __restrict__ cnt,
                                int D) {
    const int v = blockIdx.x * blockDim.x + threadIdx.x;
    const int b = blockIdx.y;
    if (v >= R3) return;
    const float c = cnt[(size_t)b * R3 + v];
    const float inv = 1.0f / fmaxf(c, 1.0f);
    float* p = vox + (size_t)b * D * R3 + v;
    for (int d = 0; d < D; ++d) p[(size_t)d * R3] *= inv;
}

extern "C" void kernel_launch(void* const* d_in, const int* in_sizes, int n_in,
                              void* d_out, int out_size, void* d_ws, size_t ws_size,
                              hipStream_t stream) {
    const float* feats  = (const float*)d_in[0];   // (B, D, N)
    const float* coords = (const float*)d_in[1];   // (B, 3, N)
    float* out = (float*)d_out;

    // Derive shapes: in_sizes[0] = B*D*N, in_sizes[1] = B*3*N,
    // out_size = B*D*R3 + B*3*N.
    const int D = (int)(3LL * in_sizes[0] / in_sizes[1]);
    const int B = (int)((long long)(out_size - in_sizes[1]) / ((long long)D * R3));
    const int N = in_sizes[1] / (3 * B);

    float* vox_out = out;                          // (B, D, R3)
    float* nc_out  = out + (size_t)B * D * R3;     // (B, 3, N)

    // Workspace layout: [mean: B*3 floats][maxn: B floats][pad to 1024B][cnt: B*R3 floats]
    float* mean = (float*)d_ws;
    float* maxn = mean + 3 * B;
    float* cnt  = (float*)((char*)d_ws + 1024);

    // Zero the accumulation targets (harness poisons them with 0xAA).
    hipMemsetAsync(vox_out, 0, (size_t)B * D * R3 * sizeof(float), stream);
    hipMemsetAsync(cnt, 0, (size_t)B * R3 * sizeof(float), stream);

    stats_kernel<<<dim3(B), dim3(256), 0, stream>>>(coords, mean, maxn, N);

    dim3 sgrid((N + 255) / 256, B);
    scatter_kernel<<<sgrid, dim3(256), 0, stream>>>(coords, feats, mean, maxn,
                                                    vox_out, nc_out, cnt, D, N);

    dim3 fgrid((R3 + 255) / 256, B);
    finalize_kernel<<<fgrid, dim3(256), 0, stream>>>(vox_out, cnt, D);
}

// Round 2
// 428.634 us; speedup vs baseline: 4.3002x; 4.3002x over previous
//
#include <hip/hip_runtime.h>

#define RES 32
#define R3 (RES * RES * RES)

// ---------------------------------------------------------------------------
// K1a: partial coordinate sums. grid (8, B), block 256.
// accum[b*4 + {0,1,2}] += chunk sums (float atomics, pre-zeroed).
// ---------------------------------------------------------------------------
__global__ void sums_kernel(const float* __restrict__ coords,
                            float* __restrict__ accum, int N) {
    const int b = blockIdx.y;
    const int stride = gridDim.x * blockDim.x;
    const float* cb = coords + (size_t)b * 3 * N;

    float s0 = 0.f, s1 = 0.f, s2 = 0.f;
    for (int n = blockIdx.x * blockDim.x + threadIdx.x; n < N; n += stride) {
        s0 += cb[n];
        s1 += cb[N + n];
        s2 += cb[2 * N + n];
    }
    for (int off = 32; off; off >>= 1) {
        s0 += __shfl_down(s0, off);
        s1 += __shfl_down(s1, off);
        s2 += __shfl_down(s2, off);
    }
    __shared__ float r0[4], r1[4], r2[4];
    const int lane = threadIdx.x & 63, wv = threadIdx.x >> 6;
    if (lane == 0) { r0[wv] = s0; r1[wv] = s1; r2[wv] = s2; }
    __syncthreads();
    if (threadIdx.x == 0) {
        float t0 = 0.f, t1 = 0.f, t2 = 0.f;
        const int nw = blockDim.x >> 6;
        for (int w = 0; w < nw; ++w) { t0 += r0[w]; t1 += r1[w]; t2 += r2[w]; }
        atomicAdd(&accum[b * 4 + 0], t0);
        atomicAdd(&accum[b * 4 + 1], t1);
        atomicAdd(&accum[b * 4 + 2], t2);
    }
}

// ---------------------------------------------------------------------------
// K1b: partial max of squared centered norm. grid (8, B), block 256.
// maxsq[b] = bitwise max over non-negative float bit patterns (pre-zeroed).
// ---------------------------------------------------------------------------
__global__ void maxn_kernel(const float* __restrict__ coords,
                            const float* __restrict__ accum,
                            unsigned* __restrict__ maxsq, int N) {
    const int b = blockIdx.y;
    const int stride = gridDim.x * blockDim.x;
    const float* cb = coords + (size_t)b * 3 * N;
    const float m0 = accum[b * 4 + 0] / (float)N;
    const float m1 = accum[b * 4 + 1] / (float)N;
    const float m2 = accum[b * 4 + 2] / (float)N;

    float mx = 0.f;
    for (int n = blockIdx.x * blockDim.x + threadIdx.x; n < N; n += stride) {
        float a = cb[n] - m0;
        float c = cb[N + n] - m1;
        float d = cb[2 * N + n] - m2;
        mx = fmaxf(mx, a * a + c * c + d * d);
    }
    for (int off = 32; off; off >>= 1) mx = fmaxf(mx, __shfl_down(mx, off));
    __shared__ float r0[4];
    const int lane = threadIdx.x & 63, wv = threadIdx.x >> 6;
    if (lane == 0) r0[wv] = mx;
    __syncthreads();
    if (threadIdx.x == 0) {
        const int nw = blockDim.x >> 6;
        for (int w = 0; w < nw; ++w) mx = fmaxf(mx, r0[w]);
        atomicMax(&maxsq[b], __float_as_uint(mx));  // all values >= 0
    }
}

// ---------------------------------------------------------------------------
// K2: per-point normalize + voxel index + counts. grid (N/256, B), block 256.
// Writes nc_out (coalesced), idx_out (coalesced), counts (int atomics).
// ---------------------------------------------------------------------------
__global__ void point_kernel(const float* __restrict__ coords,
                             const float* __restrict__ accum,
                             const unsigned* __restrict__ maxsq,
                             float* __restrict__ nc_out,
                             int* __restrict__ idx_out,
                             int* __restrict__ counts, int N) {
    const int n = blockIdx.x * blockDim.x + threadIdx.x;
    const int b = blockIdx.y;
    if (n >= N) return;

    const float* cb = coords + (size_t)b * 3 * N;
    const float m0 = accum[b * 4 + 0] / (float)N;
    const float m1 = accum[b * 4 + 1] / (float)N;
    const float m2 = accum[b * 4 + 2] / (float)N;
    const float denom = 2.0f * sqrtf(__uint_as_float(maxsq[b]));

    float c0 = (cb[n] - m0) / denom + 0.5f;
    float c1 = (cb[N + n] - m1) / denom + 0.5f;
    float c2 = (cb[2 * N + n] - m2) / denom + 0.5f;

    float v0 = fminf(fmaxf(c0 * (float)RES, 0.f), (float)(RES - 1));
    float v1 = fminf(fmaxf(c1 * (float)RES, 0.f), (float)(RES - 1));
    float v2 = fminf(fmaxf(c2 * (float)RES, 0.f), (float)(RES - 1));

    float* ncb = nc_out + (size_t)b * 3 * N;
    ncb[n] = v0;
    ncb[N + n] = v1;
    ncb[2 * N + n] = v2;

    const int i0 = (int)rintf(v0);   // round-half-even, matches jnp.round
    const int i1 = (int)rintf(v1);
    const int i2 = (int)rintf(v2);
    const int idx = i0 * RES * RES + i1 * RES + i2;

    idx_out[(size_t)b * N + n] = idx;
    atomicAdd(&counts[(size_t)b * R3 + idx], 1);
}

// ---------------------------------------------------------------------------
// K3: per-(b,d) LDS-privatized scatter-mean. grid (D, B), block 1024.
// Full 32^3 voxel grid for one dim lives in LDS (128 KB -> 1 block/CU).
// Coalesced feature-row read, LDS atomics, coalesced vox-row write.
// ---------------------------------------------------------------------------
__global__ __launch_bounds__(1024) void reduce_kernel(
        const float* __restrict__ feats,
        const int* __restrict__ idx,
        const int* __restrict__ counts,
        float* __restrict__ vox, int D, int N) {
    const int d = blockIdx.x;
    const int b = blockIdx.y;

    __shared__ float acc[R3];   // 131072 bytes
    for (int v = threadIdx.x; v < R3; v += blockDim.x) acc[v] = 0.f;
    __syncthreads();

    const float* frow = feats + ((size_t)b * D + d) * N;
    const int* irow = idx + (size_t)b * N;
    for (int n = threadIdx.x; n < N; n += blockDim.x) {
        atomicAdd(&acc[irow[n]], frow[n]);
    }
    __syncthreads();

    const int* crow = counts + (size_t)b * R3;
    float* vrow = vox + ((size_t)b * D + d) * R3;
    for (int v = threadIdx.x; v < R3; v += blockDim.x) {
        const int c = crow[v];
        vrow[v] = acc[v] / (float)(c > 1 ? c : 1);
    }
}

extern "C" void kernel_launch(void* const* d_in, const int* in_sizes, int n_in,
                              void* d_out, int out_size, void* d_ws, size_t ws_size,
                              hipStream_t stream) {
    const float* feats  = (const float*)d_in[0];   // (B, D, N)
    const float* coords = (const float*)d_in[1];   // (B, 3, N)
    float* out = (float*)d_out;

    const int D = (int)(3LL * in_sizes[0] / in_sizes[1]);
    const int B = (int)((long long)(out_size - in_sizes[1]) / ((long long)D * R3));
    const int N = in_sizes[1] / (3 * B);

    float* vox_out = out;                          // (B, D, R3)
    float* nc_out  = out + (size_t)B * D * R3;     // (B, 3, N)

    // ws layout: [accum B*4 f][maxsq B u32 @1024][idx B*N i32 @4096][counts B*R3 i32]
    float*    accum  = (float*)d_ws;
    unsigned* maxsq  = (unsigned*)((char*)d_ws + 1024);
    int*      idx    = (int*)((char*)d_ws + 4096);
    int*      counts = (int*)((char*)d_ws + 4096 + (size_t)B * N * sizeof(int));

    hipMemsetAsync(d_ws, 0, 4096, stream);                                  // accum+maxsq
    hipMemsetAsync(counts, 0, (size_t)B * R3 * sizeof(int), stream);

    sums_kernel <<<dim3(8, B), dim3(256), 0, stream>>>(coords, accum, N);
    maxn_kernel <<<dim3(8, B), dim3(256), 0, stream>>>(coords, accum, maxsq, N);

    point_kernel<<<dim3((N + 255) / 256, B), dim3(256), 0, stream>>>(
        coords, accum, maxsq, nc_out, idx, counts, N);

    reduce_kernel<<<dim3(D, B), dim3(1024), 0, stream>>>(
        feats, idx, counts, vox_out, D, N);
}

// Round 3
// 398.182 us; speedup vs baseline: 4.6291x; 1.0765x over previous
//
#include <hip/hip_runtime.h>

#define RES 32
#define R3 (RES * RES * RES)

// ---------------------------------------------------------------------------
// K1a: partial coordinate sums, float4 loads. grid (8, B), block 256.
// accum[b*4 + {0,1,2}] += chunk sums (float atomics, pre-zeroed).
// ---------------------------------------------------------------------------
__global__ void sums_kernel(const float* __restrict__ coords,
                            float* __restrict__ accum, int N) {
    const int b = blockIdx.y;
    const int stride = gridDim.x * blockDim.x;
    const float* cb = coords + (size_t)b * 3 * N;
    const int nvec = N >> 2;
    const float4* c0 = (const float4*)cb;
    const float4* c1 = (const float4*)(cb + N);
    const float4* c2 = (const float4*)(cb + 2 * N);

    float s0 = 0.f, s1 = 0.f, s2 = 0.f;
    for (int n = blockIdx.x * blockDim.x + threadIdx.x; n < nvec; n += stride) {
        float4 a = c0[n]; s0 += (a.x + a.y) + (a.z + a.w);
        float4 c = c1[n]; s1 += (c.x + c.y) + (c.z + c.w);
        float4 d = c2[n]; s2 += (d.x + d.y) + (d.z + d.w);
    }
    if (blockIdx.x == 0 && threadIdx.x == 0) {
        for (int n = nvec << 2; n < N; ++n) {
            s0 += cb[n]; s1 += cb[N + n]; s2 += cb[2 * N + n];
        }
    }
    for (int off = 32; off; off >>= 1) {
        s0 += __shfl_down(s0, off);
        s1 += __shfl_down(s1, off);
        s2 += __shfl_down(s2, off);
    }
    __shared__ float r0[4], r1[4], r2[4];
    const int lane = threadIdx.x & 63, wv = threadIdx.x >> 6;
    if (lane == 0) { r0[wv] = s0; r1[wv] = s1; r2[wv] = s2; }
    __syncthreads();
    if (threadIdx.x == 0) {
        float t0 = 0.f, t1 = 0.f, t2 = 0.f;
        const int nw = blockDim.x >> 6;
        for (int w = 0; w < nw; ++w) { t0 += r0[w]; t1 += r1[w]; t2 += r2[w]; }
        atomicAdd(&accum[b * 4 + 0], t0);
        atomicAdd(&accum[b * 4 + 1], t1);
        atomicAdd(&accum[b * 4 + 2], t2);
    }
}

// ---------------------------------------------------------------------------
// K1b: partial max squared centered norm, float4 loads. grid (8, B).
// ---------------------------------------------------------------------------
__global__ void maxn_kernel(const float* __restrict__ coords,
                            const float* __restrict__ accum,
                            unsigned* __restrict__ maxsq, int N) {
    const int b = blockIdx.y;
    const int stride = gridDim.x * blockDim.x;
    const float* cb = coords + (size_t)b * 3 * N;
    const float m0 = accum[b * 4 + 0] / (float)N;
    const float m1 = accum[b * 4 + 1] / (float)N;
    const float m2 = accum[b * 4 + 2] / (float)N;
    const int nvec = N >> 2;
    const float4* c0 = (const float4*)cb;
    const float4* c1 = (const float4*)(cb + N);
    const float4* c2 = (const float4*)(cb + 2 * N);

    float mx = 0.f;
    for (int n = blockIdx.x * blockDim.x + threadIdx.x; n < nvec; n += stride) {
        float4 a = c0[n], c = c1[n], d = c2[n];
        a.x -= m0; a.y -= m0; a.z -= m0; a.w -= m0;
        c.x -= m1; c.y -= m1; c.z -= m1; c.w -= m1;
        d.x -= m2; d.y -= m2; d.z -= m2; d.w -= m2;
        mx = fmaxf(mx, a.x * a.x + c.x * c.x + d.x * d.x);
        mx = fmaxf(mx, a.y * a.y + c.y * c.y + d.y * d.y);
        mx = fmaxf(mx, a.z * a.z + c.z * c.z + d.z * d.z);
        mx = fmaxf(mx, a.w * a.w + c.w * c.w + d.w * d.w);
    }
    if (blockIdx.x == 0 && threadIdx.x == 0) {
        for (int n = nvec << 2; n < N; ++n) {
            float a = cb[n] - m0, c = cb[N + n] - m1, d = cb[2 * N + n] - m2;
            mx = fmaxf(mx, a * a + c * c + d * d);
        }
    }
    for (int off = 32; off; off >>= 1) mx = fmaxf(mx, __shfl_down(mx, off));
    __shared__ float r0[4];
    const int lane = threadIdx.x & 63, wv = threadIdx.x >> 6;
    if (lane == 0) r0[wv] = mx;
    __syncthreads();
    if (threadIdx.x == 0) {
        const int nw = blockDim.x >> 6;
        for (int w = 0; w < nw; ++w) mx = fmaxf(mx, r0[w]);
        atomicMax(&maxsq[b], __float_as_uint(mx));  // all values >= 0
    }
}

// ---------------------------------------------------------------------------
// K2: per-point normalize + voxel index + counts, 4 points/thread.
// grid (ceil(N/4/256), B), block 256.
// ---------------------------------------------------------------------------
__global__ void point_kernel(const float* __restrict__ coords,
                             const float* __restrict__ accum,
                             const unsigned* __restrict__ maxsq,
                             float* __restrict__ nc_out,
                             int* __restrict__ idx_out,
                             int* __restrict__ counts, int N) {
    const int n4 = blockIdx.x * blockDim.x + threadIdx.x;
    const int b = blockIdx.y;
    const int nvec = (N + 3) >> 2;
    if (n4 >= nvec) return;

    const float* cb = coords + (size_t)b * 3 * N;
    const float m0 = accum[b * 4 + 0] / (float)N;
    const float m1 = accum[b * 4 + 1] / (float)N;
    const float m2 = accum[b * 4 + 2] / (float)N;
    const float inv = 1.0f / (2.0f * sqrtf(__uint_as_float(maxsq[b])));
    float* ncb = nc_out + (size_t)b * 3 * N;
    int* irow = idx_out + (size_t)b * N;
    int* crow = counts + (size_t)b * R3;

    const int n0 = n4 << 2;
    if (n0 + 3 < N) {
        float4 a = *(const float4*)(cb + n0);
        float4 c = *(const float4*)(cb + N + n0);
        float4 d = *(const float4*)(cb + 2 * N + n0);
        float4 v0, v1, v2;
        int4 id;
        #define PROC(comp)                                                        \
        {                                                                         \
            float x = (a.comp - m0) * inv + 0.5f;                                 \
            float y = (c.comp - m1) * inv + 0.5f;                                 \
            float z = (d.comp - m2) * inv + 0.5f;                                 \
            v0.comp = fminf(fmaxf(x * (float)RES, 0.f), (float)(RES - 1));        \
            v1.comp = fminf(fmaxf(y * (float)RES, 0.f), (float)(RES - 1));        \
            v2.comp = fminf(fmaxf(z * (float)RES, 0.f), (float)(RES - 1));        \
            id.comp = (int)rintf(v0.comp) * RES * RES                             \
                    + (int)rintf(v1.comp) * RES + (int)rintf(v2.comp);            \
        }
        PROC(x) PROC(y) PROC(z) PROC(w)
        #undef PROC
        *(float4*)(ncb + n0) = v0;
        *(float4*)(ncb + N + n0) = v1;
        *(float4*)(ncb + 2 * N + n0) = v2;
        *(int4*)(irow + n0) = id;
        atomicAdd(&crow[id.x], 1);
        atomicAdd(&crow[id.y], 1);
        atomicAdd(&crow[id.z], 1);
        atomicAdd(&crow[id.w], 1);
    } else {
        for (int n = n0; n < N; ++n) {
            float x = (cb[n] - m0) * inv + 0.5f;
            float y = (cb[N + n] - m1) * inv + 0.5f;
            float z = (cb[2 * N + n] - m2) * inv + 0.5f;
            float v0 = fminf(fmaxf(x * (float)RES, 0.f), (float)(RES - 1));
            float v1 = fminf(fmaxf(y * (float)RES, 0.f), (float)(RES - 1));
            float v2 = fminf(fmaxf(z * (float)RES, 0.f), (float)(RES - 1));
            ncb[n] = v0; ncb[N + n] = v1; ncb[2 * N + n] = v2;
            int id = (int)rintf(v0) * RES * RES + (int)rintf(v1) * RES + (int)rintf(v2);
            irow[n] = id;
            atomicAdd(&crow[id], 1);
        }
    }
}

// ---------------------------------------------------------------------------
// K3: per-(b,d) LDS-privatized scatter-mean, float4/int4 everywhere.
// grid (D, B), block 1024. 128 KB LDS -> 1 block/CU, 16 waves.
// ---------------------------------------------------------------------------
__global__ __launch_bounds__(1024) void reduce_kernel(
        const float* __restrict__ feats,
        const int* __restrict__ idx,
        const int* __restrict__ counts,
        float* __restrict__ vox, int D, int N) {
    const int d = blockIdx.x;
    const int b = blockIdx.y;
    const int tid = threadIdx.x;

    __shared__ float acc[R3];   // 131072 bytes
    {
        float4* a4 = (float4*)acc;
        const float4 z = make_float4(0.f, 0.f, 0.f, 0.f);
        for (int v = tid; v < (R3 >> 2); v += blockDim.x) a4[v] = z;
    }
    __syncthreads();

    const float* frow = feats + ((size_t)b * D + d) * N;
    const int* irow = idx + (size_t)b * N;
    const int nvec = N >> 2;
    const float4* f4 = (const float4*)frow;
    const int4* i4 = (const int4*)irow;
    for (int n = tid; n < nvec; n += blockDim.x) {
        float4 f = f4[n];
        int4 i = i4[n];
        atomicAdd(&acc[i.x], f.x);
        atomicAdd(&acc[i.y], f.y);
        atomicAdd(&acc[i.z], f.z);
        atomicAdd(&acc[i.w], f.w);
    }
    if (tid == 0) {
        for (int n = nvec << 2; n < N; ++n) atomicAdd(&acc[irow[n]], frow[n]);
    }
    __syncthreads();

    const int* crow = counts + (size_t)b * R3;
    float* vrow = vox + ((size_t)b * D + d) * R3;
    const int4* c4 = (const int4*)crow;
    float4* v4 = (float4*)vrow;
    for (int v = tid; v < (R3 >> 2); v += blockDim.x) {
        int4 c = c4[v];
        float4 a = ((const float4*)acc)[v];
        a.x /= (float)(c.x > 1 ? c.x : 1);
        a.y /= (float)(c.y > 1 ? c.y : 1);
        a.z /= (float)(c.z > 1 ? c.z : 1);
        a.w /= (float)(c.w > 1 ? c.w : 1);
        v4[v] = a;
    }
}

extern "C" void kernel_launch(void* const* d_in, const int* in_sizes, int n_in,
                              void* d_out, int out_size, void* d_ws, size_t ws_size,
                              hipStream_t stream) {
    const float* feats  = (const float*)d_in[0];   // (B, D, N)
    const float* coords = (const float*)d_in[1];   // (B, 3, N)
    float* out = (float*)d_out;

    const int D = (int)(3LL * in_sizes[0] / in_sizes[1]);
    const int B = (int)((long long)(out_size - in_sizes[1]) / ((long long)D * R3));
    const int N = in_sizes[1] / (3 * B);

    float* vox_out = out;                          // (B, D, R3)
    float* nc_out  = out + (size_t)B * D * R3;     // (B, 3, N)

    // ws layout: [accum B*4 f @0][maxsq B u32 @1024][counts B*R3 i32 @4096][idx B*N i32]
    float*    accum  = (float*)d_ws;
    unsigned* maxsq  = (unsigned*)((char*)d_ws + 1024);
    int*      counts = (int*)((char*)d_ws + 4096);
    int*      idx    = (int*)((char*)d_ws + 4096 + (size_t)B * R3 * sizeof(int));

    // single memset covers accum+maxsq+counts (contiguous)
    hipMemsetAsync(d_ws, 0, 4096 + (size_t)B * R3 * sizeof(int), stream);

    sums_kernel <<<dim3(8, B), dim3(256), 0, stream>>>(coords, accum, N);
    maxn_kernel <<<dim3(8, B), dim3(256), 0, stream>>>(coords, accum, maxsq, N);

    const int nvec = (N + 3) >> 2;
    point_kernel<<<dim3((nvec + 255) / 256, B), dim3(256), 0, stream>>>(
        coords, accum, maxsq, nc_out, idx, counts, N);

    reduce_kernel<<<dim3(D, B), dim3(1024), 0, stream>>>(
        feats, idx, counts, vox_out, D, N);
}

// Round 4
// 395.860 us; speedup vs baseline: 4.6562x; 1.0059x over previous
//
#include <hip/hip_runtime.h>

#define RES 32
#define R3 (RES * RES * RES)

// Native no-return fp32 atomic add (ds_add_f32 / global_atomic_add_f32).
// Plain atomicAdd(float*) lowers to a CAS retry loop without
// -munsafe-fp-atomics; with hot voxels that cost ~234 cyc/wave-instr (R3 pm).
__device__ __forceinline__ void fadd_native(float* p, float v) {
    unsafeAtomicAdd(p, v);
}

// ---------------------------------------------------------------------------
// K1a: partial coordinate sums, float4 loads. grid (8, B), block 256.
// ---------------------------------------------------------------------------
__global__ void sums_kernel(const float* __restrict__ coords,
                            float* __restrict__ accum, int N) {
    const int b = blockIdx.y;
    const int stride = gridDim.x * blockDim.x;
    const float* cb = coords + (size_t)b * 3 * N;
    const int nvec = N >> 2;
    const float4* c0 = (const float4*)cb;
    const float4* c1 = (const float4*)(cb + N);
    const float4* c2 = (const float4*)(cb + 2 * N);

    float s0 = 0.f, s1 = 0.f, s2 = 0.f;
    for (int n = blockIdx.x * blockDim.x + threadIdx.x; n < nvec; n += stride) {
        float4 a = c0[n]; s0 += (a.x + a.y) + (a.z + a.w);
        float4 c = c1[n]; s1 += (c.x + c.y) + (c.z + c.w);
        float4 d = c2[n]; s2 += (d.x + d.y) + (d.z + d.w);
    }
    if (blockIdx.x == 0 && threadIdx.x == 0) {
        for (int n = nvec << 2; n < N; ++n) {
            s0 += cb[n]; s1 += cb[N + n]; s2 += cb[2 * N + n];
        }
    }
    for (int off = 32; off; off >>= 1) {
        s0 += __shfl_down(s0, off);
        s1 += __shfl_down(s1, off);
        s2 += __shfl_down(s2, off);
    }
    __shared__ float r0[4], r1[4], r2[4];
    const int lane = threadIdx.x & 63, wv = threadIdx.x >> 6;
    if (lane == 0) { r0[wv] = s0; r1[wv] = s1; r2[wv] = s2; }
    __syncthreads();
    if (threadIdx.x == 0) {
        float t0 = 0.f, t1 = 0.f, t2 = 0.f;
        const int nw = blockDim.x >> 6;
        for (int w = 0; w < nw; ++w) { t0 += r0[w]; t1 += r1[w]; t2 += r2[w]; }
        fadd_native(&accum[b * 4 + 0], t0);
        fadd_native(&accum[b * 4 + 1], t1);
        fadd_native(&accum[b * 4 + 2], t2);
    }
}

// ---------------------------------------------------------------------------
// K1b: partial max squared centered norm, float4 loads. grid (8, B).
// ---------------------------------------------------------------------------
__global__ void maxn_kernel(const float* __restrict__ coords,
                            const float* __restrict__ accum,
                            unsigned* __restrict__ maxsq, int N) {
    const int b = blockIdx.y;
    const int stride = gridDim.x * blockDim.x;
    const float* cb = coords + (size_t)b * 3 * N;
    const float m0 = accum[b * 4 + 0] / (float)N;
    const float m1 = accum[b * 4 + 1] / (float)N;
    const float m2 = accum[b * 4 + 2] / (float)N;
    const int nvec = N >> 2;
    const float4* c0 = (const float4*)cb;
    const float4* c1 = (const float4*)(cb + N);
    const float4* c2 = (const float4*)(cb + 2 * N);

    float mx = 0.f;
    for (int n = blockIdx.x * blockDim.x + threadIdx.x; n < nvec; n += stride) {
        float4 a = c0[n], c = c1[n], d = c2[n];
        a.x -= m0; a.y -= m0; a.z -= m0; a.w -= m0;
        c.x -= m1; c.y -= m1; c.z -= m1; c.w -= m1;
        d.x -= m2; d.y -= m2; d.z -= m2; d.w -= m2;
        mx = fmaxf(mx, a.x * a.x + c.x * c.x + d.x * d.x);
        mx = fmaxf(mx, a.y * a.y + c.y * c.y + d.y * d.y);
        mx = fmaxf(mx, a.z * a.z + c.z * c.z + d.z * d.z);
        mx = fmaxf(mx, a.w * a.w + c.w * c.w + d.w * d.w);
    }
    if (blockIdx.x == 0 && threadIdx.x == 0) {
        for (int n = nvec << 2; n < N; ++n) {
            float a = cb[n] - m0, c = cb[N + n] - m1, d = cb[2 * N + n] - m2;
            mx = fmaxf(mx, a * a + c * c + d * d);
        }
    }
    for (int off = 32; off; off >>= 1) mx = fmaxf(mx, __shfl_down(mx, off));
    __shared__ float r0[4];
    const int lane = threadIdx.x & 63, wv = threadIdx.x >> 6;
    if (lane == 0) r0[wv] = mx;
    __syncthreads();
    if (threadIdx.x == 0) {
        const int nw = blockDim.x >> 6;
        for (int w = 0; w < nw; ++w) mx = fmaxf(mx, r0[w]);
        atomicMax(&maxsq[b], __float_as_uint(mx));  // int atomic: native
    }
}

// ---------------------------------------------------------------------------
// K2: per-point normalize + voxel index + counts, 4 points/thread.
// True division (not rcp-mul) to keep voxel indices bit-identical to ref.
// ---------------------------------------------------------------------------
__global__ void point_kernel(const float* __restrict__ coords,
                             const float* __restrict__ accum,
                             const unsigned* __restrict__ maxsq,
                             float* __restrict__ nc_out,
                             int* __restrict__ idx_out,
                             int* __restrict__ counts, int N) {
    const int n4 = blockIdx.x * blockDim.x + threadIdx.x;
    const int b = blockIdx.y;
    const int nvec = (N + 3) >> 2;
    if (n4 >= nvec) return;

    const float* cb = coords + (size_t)b * 3 * N;
    const float m0 = accum[b * 4 + 0] / (float)N;
    const float m1 = accum[b * 4 + 1] / (float)N;
    const float m2 = accum[b * 4 + 2] / (float)N;
    const float denom = 2.0f * sqrtf(__uint_as_float(maxsq[b]));
    float* ncb = nc_out + (size_t)b * 3 * N;
    int* irow = idx_out + (size_t)b * N;
    int* crow = counts + (size_t)b * R3;

    const int n0 = n4 << 2;
    if (n0 + 3 < N) {
        float4 a = *(const float4*)(cb + n0);
        float4 c = *(const float4*)(cb + N + n0);
        float4 d = *(const float4*)(cb + 2 * N + n0);
        float4 v0, v1, v2;
        int4 id;
        #define PROC(comp)                                                        \
        {                                                                         \
            float x = (a.comp - m0) / denom + 0.5f;                               \
            float y = (c.comp - m1) / denom + 0.5f;                               \
            float z = (d.comp - m2) / denom + 0.5f;                               \
            v0.comp = fminf(fmaxf(x * (float)RES, 0.f), (float)(RES - 1));        \
            v1.comp = fminf(fmaxf(y * (float)RES, 0.f), (float)(RES - 1));        \
            v2.comp = fminf(fmaxf(z * (float)RES, 0.f), (float)(RES - 1));        \
            id.comp = (int)rintf(v0.comp) * RES * RES                             \
                    + (int)rintf(v1.comp) * RES + (int)rintf(v2.comp);            \
        }
        PROC(x) PROC(y) PROC(z) PROC(w)
        #undef PROC
        *(float4*)(ncb + n0) = v0;
        *(float4*)(ncb + N + n0) = v1;
        *(float4*)(ncb + 2 * N + n0) = v2;
        *(int4*)(irow + n0) = id;
        atomicAdd(&crow[id.x], 1);
        atomicAdd(&crow[id.y], 1);
        atomicAdd(&crow[id.z], 1);
        atomicAdd(&crow[id.w], 1);
    } else {
        for (int n = n0; n < N; ++n) {
            float x = (cb[n] - m0) / denom + 0.5f;
            float y = (cb[N + n] - m1) / denom + 0.5f;
            float z = (cb[2 * N + n] - m2) / denom + 0.5f;
            float v0 = fminf(fmaxf(x * (float)RES, 0.f), (float)(RES - 1));
            float v1 = fminf(fmaxf(y * (float)RES, 0.f), (float)(RES - 1));
            float v2 = fminf(fmaxf(z * (float)RES, 0.f), (float)(RES - 1));
            ncb[n] = v0; ncb[N + n] = v1; ncb[2 * N + n] = v2;
            int id = (int)rintf(v0) * RES * RES + (int)rintf(v1) * RES + (int)rintf(v2);
            irow[n] = id;
            atomicAdd(&crow[id], 1);
        }
    }
}

// ---------------------------------------------------------------------------
// K3: per-(b,d) LDS-privatized scatter-mean, float4/int4, native ds_add_f32.
// grid (D, B), block 1024. 128 KB LDS -> 1 block/CU, 16 waves.
// ---------------------------------------------------------------------------
__global__ __launch_bounds__(1024) void reduce_kernel(
        const float* __restrict__ feats,
        const int* __restrict__ idx,
        const int* __restrict__ counts,
        float* __restrict__ vox, int D, int N) {
    const int d = blockIdx.x;
    const int b = blockIdx.y;
    const int tid = threadIdx.x;

    __shared__ float acc[R3];   // 131072 bytes
    {
        float4* a4 = (float4*)acc;
        const float4 z = make_float4(0.f, 0.f, 0.f, 0.f);
        for (int v = tid; v < (R3 >> 2); v += blockDim.x) a4[v] = z;
    }
    __syncthreads();

    const float* frow = feats + ((size_t)b * D + d) * N;
    const int* irow = idx + (size_t)b * N;
    const int nvec = N >> 2;
    const float4* f4 = (const float4*)frow;
    const int4* i4 = (const int4*)irow;
    for (int n = tid; n < nvec; n += blockDim.x) {
        float4 f = f4[n];
        int4 i = i4[n];
        fadd_native(&acc[i.x], f.x);
        fadd_native(&acc[i.y], f.y);
        fadd_native(&acc[i.z], f.z);
        fadd_native(&acc[i.w], f.w);
    }
    if (tid == 0) {
        for (int n = nvec << 2; n < N; ++n) fadd_native(&acc[irow[n]], frow[n]);
    }
    __syncthreads();

    const int* crow = counts + (size_t)b * R3;
    float* vrow = vox + ((size_t)b * D + d) * R3;
    const int4* c4 = (const int4*)crow;
    float4* v4 = (float4*)vrow;
    for (int v = tid; v < (R3 >> 2); v += blockDim.x) {
        int4 c = c4[v];
        float4 a = ((const float4*)acc)[v];
        a.x /= (float)(c.x > 1 ? c.x : 1);
        a.y /= (float)(c.y > 1 ? c.y : 1);
        a.z /= (float)(c.z > 1 ? c.z : 1);
        a.w /= (float)(c.w > 1 ? c.w : 1);
        v4[v] = a;
    }
}

extern "C" void kernel_launch(void* const* d_in, const int* in_sizes, int n_in,
                              void* d_out, int out_size, void* d_ws, size_t ws_size,
                              hipStream_t stream) {
    const float* feats  = (const float*)d_in[0];   // (B, D, N)
    const float* coords = (const float*)d_in[1];   // (B, 3, N)
    float* out = (float*)d_out;

    const int D = (int)(3LL * in_sizes[0] / in_sizes[1]);
    const int B = (int)((long long)(out_size - in_sizes[1]) / ((long long)D * R3));
    const int N = in_sizes[1] / (3 * B);

    float* vox_out = out;                          // (B, D, R3)
    float* nc_out  = out + (size_t)B * D * R3;     // (B, 3, N)

    // ws layout: [accum B*4 f @0][maxsq B u32 @1024][counts B*R3 i32 @4096][idx B*N i32]
    float*    accum  = (float*)d_ws;
    unsigned* maxsq  = (unsigned*)((char*)d_ws + 1024);
    int*      counts = (int*)((char*)d_ws + 4096);
    int*      idx    = (int*)((char*)d_ws + 4096 + (size_t)B * R3 * sizeof(int));

    hipMemsetAsync(d_ws, 0, 4096 + (size_t)B * R3 * sizeof(int), stream);

    sums_kernel <<<dim3(8, B), dim3(256), 0, stream>>>(coords, accum, N);
    maxn_kernel <<<dim3(8, B), dim3(256), 0, stream>>>(coords, accum, maxsq, N);

    const int nvec = (N + 3) >> 2;
    point_kernel<<<dim3((nvec + 255) / 256, B), dim3(256), 0, stream>>>(
        coords, accum, maxsq, nc_out, idx, counts, N);

    reduce_kernel<<<dim3(D, B), dim3(1024), 0, stream>>>(
        feats, idx, counts, vox_out, D, N);
}